// Round 11
// baseline (70.212 us; speedup 1.0000x reference)
//
#include <hip/hip_runtime.h>

// loss_separation: sum_{b, i != j} exp(-0.5 * ||kp[b,i] - kp[b,j]||)
// B=32, N=2048 fp32 -> scalar fp32.
// Symmetry: 2*sum_{i<j}; upper-tri 128x128 tile pairs; partials->d_ws + reduce.
// R7: Schraudolph exp2 (fma+cvt) replaces v_exp_f32; SoA LDS + v_pk f32 math.
// R8: LDS-BW fix — 64-thread blocks, 2 i-points/thread: each ds_read_b128
// pair now feeds 8 pair-evals (256 B/pair-unit, ~49 B/cy/CU demand vs ~85
// ceiling) -> VALU-bound again. Tile/diag logic unchanged.

#define BATCHES 32
#define NPTS 2048
#define TILE 128
#define TTILES (NPTS / TILE)                 // 16
#define NTPAIRS (TTILES * (TTILES + 1) / 2)  // 136
#define NPARTS (NTPAIRS * BATCHES)           // 4352 = 17 * 256

typedef float vf2 __attribute__((ext_vector_type(2)));
typedef float vf4 __attribute__((ext_vector_type(4)));

// exp2(x) ~= asfloat((int)(x*2^23 + BF)), x <= 0 here.
// K folds -0.5*log2(e) and 2^23. BF = (127 - 0.0564)*2^23 + 0.5.
#define K_EXP  (-6051102.0f)        // -0.72134752 * 8388608
#define BF_EXP (1064880100.0f)      // (127 - 0.0564) * 2^23 + 0.5

__global__ __launch_bounds__(64)
void loss_sep_kernel(const float2* __restrict__ kp, float* __restrict__ part) {
    const int b = blockIdx.y;

    // Decode upper-triangular tile pair (ti <= tj); uniform SALU loop <=16 iters.
    int t = blockIdx.x;
    int ti = 0;
    while (t >= TTILES - ti) { t -= TTILES - ti; ++ti; }
    const int tj = ti + t;
    const bool diag = (ti == tj);

    const int i0 = ti * TILE;
    const int j0 = tj * TILE;
    const int tid = threadIdx.x;   // 0..63, one wave

    __shared__ float kjx[TILE];    // SoA so b128 gives 4 consecutive x's
    __shared__ float kjy[TILE];
    {
        const float2 v0 = kp[(size_t)b * NPTS + j0 + tid];
        const float2 v1 = kp[(size_t)b * NPTS + j0 + 64 + tid];
        kjx[tid] = v0.x;      kjy[tid] = v0.y;
        kjx[64 + tid] = v1.x; kjy[64 + tid] = v1.y;
    }
    const float2 kia = kp[(size_t)b * NPTS + i0 + tid];        // i-point A
    const float2 kib = kp[(size_t)b * NPTS + i0 + 64 + tid];   // i-point B
    __syncthreads();

    const vf4* xs4 = reinterpret_cast<const vf4*>(kjx);
    const vf4* ys4 = reinterpret_cast<const vf4*>(kjy);
    const vf2 kxa = {kia.x, kia.x}, kya = {kia.y, kia.y};
    const vf2 kxb = {kib.x, kib.x}, kyb = {kib.y, kib.y};

    vf2 accA = {0.0f, 0.0f}, accB = {0.0f, 0.0f};
    vf2 accC = {0.0f, 0.0f}, accD = {0.0f, 0.0f};
    #pragma unroll 4
    for (int jj = 0; jj < TILE / 4; ++jj) {
        const vf4 xs = xs4[jj];              // ds_read_b128 broadcast
        const vf4 ys = ys4[jj];
        // i-point A vs 4 j's
        {
            const vf2 dx01 = kxa - xs.lo, dy01 = kya - ys.lo;
            const vf2 dx23 = kxa - xs.hi, dy23 = kya - ys.hi;
            const vf2 d01 = dx01 * dx01 + dy01 * dy01;  // v_pk_mul + v_pk_fma
            const vf2 d23 = dx23 * dx23 + dy23 * dy23;
            const int e0 = (int)fmaf(__builtin_amdgcn_sqrtf(d01.x), K_EXP, BF_EXP);
            const int e1 = (int)fmaf(__builtin_amdgcn_sqrtf(d01.y), K_EXP, BF_EXP);
            const int e2 = (int)fmaf(__builtin_amdgcn_sqrtf(d23.x), K_EXP, BF_EXP);
            const int e3 = (int)fmaf(__builtin_amdgcn_sqrtf(d23.y), K_EXP, BF_EXP);
            accA += (vf2){__int_as_float(e0), __int_as_float(e1)};
            accB += (vf2){__int_as_float(e2), __int_as_float(e3)};
        }
        // i-point B vs the same 4 j's (reuses the LDS read)
        {
            const vf2 dx01 = kxb - xs.lo, dy01 = kyb - ys.lo;
            const vf2 dx23 = kxb - xs.hi, dy23 = kyb - ys.hi;
            const vf2 d01 = dx01 * dx01 + dy01 * dy01;
            const vf2 d23 = dx23 * dx23 + dy23 * dy23;
            const int e0 = (int)fmaf(__builtin_amdgcn_sqrtf(d01.x), K_EXP, BF_EXP);
            const int e1 = (int)fmaf(__builtin_amdgcn_sqrtf(d01.y), K_EXP, BF_EXP);
            const int e2 = (int)fmaf(__builtin_amdgcn_sqrtf(d23.x), K_EXP, BF_EXP);
            const int e3 = (int)fmaf(__builtin_amdgcn_sqrtf(d23.y), K_EXP, BF_EXP);
            accC += (vf2){__int_as_float(e0), __int_as_float(e1)};
            accD += (vf2){__int_as_float(e2), __int_as_float(e3)};
        }
    }
    const vf2 accp = (accA + accB) + (accC + accD);
    float acc = accp.x + accp.y;
    // Diagonal tile: j==i_a and j==i_b each contributed exactly
    // asfloat((int)BF_EXP) (s==0). Remove both.
    if (diag) acc -= 2.0f * __int_as_float((int)BF_EXP);

    // Wave-64 butterfly reduce (single wave per block)
    #pragma unroll
    for (int off = 32; off > 0; off >>= 1)
        acc += __shfl_down(acc, off, 64);

    if (tid == 0) {
        if (!diag) acc *= 2.0f;  // unordered pair counted once -> weight 2
        part[b * NTPAIRS + blockIdx.x] = acc;  // contention-free store
    }
}

__global__ __launch_bounds__(256)
void loss_sep_reduce(const float* __restrict__ part, float* __restrict__ out) {
    const int tid = threadIdx.x;
    float acc = 0.0f;
    #pragma unroll
    for (int k = 0; k < NPARTS / 256; ++k)      // 17 coalesced strided loads
        acc += part[k * 256 + tid];

    #pragma unroll
    for (int off = 32; off > 0; off >>= 1)
        acc += __shfl_down(acc, off, 64);

    __shared__ float wsum[4];
    if ((tid & 63) == 0) wsum[tid >> 6] = acc;
    __syncthreads();

    if (tid == 0)
        out[0] = wsum[0] + wsum[1] + wsum[2] + wsum[3];
}

extern "C" void kernel_launch(void* const* d_in, const int* in_sizes, int n_in,
                              void* d_out, int out_size, void* d_ws, size_t ws_size,
                              hipStream_t stream) {
    const float2* kp = (const float2*)d_in[0];
    float* part = (float*)d_ws;   // NPARTS floats, fully overwritten each call
    float* out = (float*)d_out;

    dim3 grid(NTPAIRS, BATCHES);  // 136 x 32 = 4352 one-wave blocks = 17/CU
    loss_sep_kernel<<<grid, 64, 0, stream>>>(kp, part);
    loss_sep_reduce<<<1, 256, 0, stream>>>(part, out);
}

// Round 12
// 69.242 us; speedup vs baseline: 1.0140x; 1.0140x over previous
//
#include <hip/hip_runtime.h>

// loss_separation: sum_{b, i != j} exp(-0.5 * ||kp[b,i] - kp[b,j]||)
// B=32, N=2048 fp32 -> scalar fp32.
// R12: rect tiles 256i x 64j, 128-thread blocks, 2 i-points/thread.
// Same occupancy as R7 (2-wave blocks, 36 waves/CU issued) but each
// ds_read_b128 pair feeds 8 pair-evals -> LDS pipe 10.9 -> 5.4 us.
// Coverage: tiles tj>=4ti; tj>=4ti+4 strictly above diag (weight 2);
// 4 straddle tiles/row hold within-block pairs both orders (weight 1)
// + exact Schraudolph-diag correction.

#define BATCHES 32
#define NPTS 2048
#define TI 256                    // i-extent per block (2 per thread)
#define TJ 64                     // j-extent per block
#define NTI (NPTS / TI)           // 8
#define NTJ (NPTS / TJ)           // 32
#define NTILES 144                // sum_{ti=0..7} (32 - 4*ti)
#define NPARTS (NTILES * BATCHES) // 4608 = 18 * 256

typedef float vf2 __attribute__((ext_vector_type(2)));
typedef float vf4 __attribute__((ext_vector_type(4)));

// exp2(x) ~= asfloat((int)(x*2^23 + BF)), x <= 0 here.
// K folds -0.5*log2(e) and 2^23. BF = (127 - 0.0564)*2^23 + 0.5.
#define K_EXP  (-6051102.0f)        // -0.72134752 * 8388608
#define BF_EXP (1064880100.0f)      // (127 - 0.0564) * 2^23 + 0.5

__global__ __launch_bounds__(128)
void loss_sep_kernel(const float2* __restrict__ kp, float* __restrict__ part) {
    const int b = blockIdx.y;

    // Decode tile: row ti has NTJ - 4*ti tiles starting at tj = 4*ti.
    int t = blockIdx.x;
    int ti = 0;
    while (t >= NTJ - 4 * ti) { t -= NTJ - 4 * ti; ++ti; }
    const int tj = 4 * ti + t;
    const bool straddle = (t < 4);   // j-range inside this 256-i-block

    const int i0 = ti * TI;
    const int j0 = tj * TJ;
    const int tid = threadIdx.x;     // 0..127, two waves

    __shared__ float kjx[TJ];        // SoA: b128 = 4 consecutive x's
    __shared__ float kjy[TJ];
    if (tid < TJ) {
        const float2 v = kp[(size_t)b * NPTS + j0 + tid];
        kjx[tid] = v.x;
        kjy[tid] = v.y;
    }
    const float2 kia = kp[(size_t)b * NPTS + i0 + tid];         // i-point A
    const float2 kib = kp[(size_t)b * NPTS + i0 + 128 + tid];   // i-point B
    __syncthreads();

    const vf4* xs4 = reinterpret_cast<const vf4*>(kjx);
    const vf4* ys4 = reinterpret_cast<const vf4*>(kjy);
    const vf2 kxa = {kia.x, kia.x}, kya = {kia.y, kia.y};
    const vf2 kxb = {kib.x, kib.x}, kyb = {kib.y, kib.y};

    vf2 accA = {0.0f, 0.0f}, accB = {0.0f, 0.0f};
    vf2 accC = {0.0f, 0.0f}, accD = {0.0f, 0.0f};
    #pragma unroll
    for (int jj = 0; jj < TJ / 4; ++jj) {        // 16 iters, 4 j's each
        const vf4 xs = xs4[jj];                  // ds_read_b128 broadcast
        const vf4 ys = ys4[jj];
        // i-point A vs 4 j's
        {
            const vf2 dx01 = kxa - xs.lo, dy01 = kya - ys.lo;
            const vf2 dx23 = kxa - xs.hi, dy23 = kya - ys.hi;
            const vf2 d01 = dx01 * dx01 + dy01 * dy01;
            const vf2 d23 = dx23 * dx23 + dy23 * dy23;
            const int e0 = (int)fmaf(__builtin_amdgcn_sqrtf(d01.x), K_EXP, BF_EXP);
            const int e1 = (int)fmaf(__builtin_amdgcn_sqrtf(d01.y), K_EXP, BF_EXP);
            const int e2 = (int)fmaf(__builtin_amdgcn_sqrtf(d23.x), K_EXP, BF_EXP);
            const int e3 = (int)fmaf(__builtin_amdgcn_sqrtf(d23.y), K_EXP, BF_EXP);
            accA += (vf2){__int_as_float(e0), __int_as_float(e1)};
            accB += (vf2){__int_as_float(e2), __int_as_float(e3)};
        }
        // i-point B vs the same 4 j's (reuses the LDS read)
        {
            const vf2 dx01 = kxb - xs.lo, dy01 = kyb - ys.lo;
            const vf2 dx23 = kxb - xs.hi, dy23 = kyb - ys.hi;
            const vf2 d01 = dx01 * dx01 + dy01 * dy01;
            const vf2 d23 = dx23 * dx23 + dy23 * dy23;
            const int e0 = (int)fmaf(__builtin_amdgcn_sqrtf(d01.x), K_EXP, BF_EXP);
            const int e1 = (int)fmaf(__builtin_amdgcn_sqrtf(d01.y), K_EXP, BF_EXP);
            const int e2 = (int)fmaf(__builtin_amdgcn_sqrtf(d23.x), K_EXP, BF_EXP);
            const int e3 = (int)fmaf(__builtin_amdgcn_sqrtf(d23.y), K_EXP, BF_EXP);
            accC += (vf2){__int_as_float(e0), __int_as_float(e1)};
            accD += (vf2){__int_as_float(e2), __int_as_float(e3)};
        }
    }
    const vf2 accp = (accA + accB) + (accC + accD);
    float acc = accp.x + accp.y;

    if (straddle) {
        // Diagonal j==i contributed exactly asfloat((int)BF_EXP) per hit.
        // i_A hits iff t == tid>>6 ; i_B hits iff t == (tid>>6) + 2.
        const int g = tid >> 6;
        float corr = 0.0f;
        if (t == g)     corr += 1.0f;
        if (t == g + 2) corr += 1.0f;
        acc -= corr * __int_as_float((int)BF_EXP);
    }

    // Wave-64 butterfly reduce, then combine 2 waves
    #pragma unroll
    for (int off = 32; off > 0; off >>= 1)
        acc += __shfl_down(acc, off, 64);

    __shared__ float wsum[2];
    if ((tid & 63) == 0) wsum[tid >> 6] = acc;
    __syncthreads();

    if (tid == 0) {
        float tot = wsum[0] + wsum[1];
        if (!straddle) tot *= 2.0f;  // strictly-above-diagonal tile -> weight 2
        part[b * NTILES + blockIdx.x] = tot;  // contention-free store
    }
}

__global__ __launch_bounds__(256)
void loss_sep_reduce(const float* __restrict__ part, float* __restrict__ out) {
    const int tid = threadIdx.x;
    float acc = 0.0f;
    #pragma unroll
    for (int k = 0; k < NPARTS / 256; ++k)      // 18 coalesced strided loads
        acc += part[k * 256 + tid];

    #pragma unroll
    for (int off = 32; off > 0; off >>= 1)
        acc += __shfl_down(acc, off, 64);

    __shared__ float wsum[4];
    if ((tid & 63) == 0) wsum[tid >> 6] = acc;
    __syncthreads();

    if (tid == 0)
        out[0] = wsum[0] + wsum[1] + wsum[2] + wsum[3];
}

extern "C" void kernel_launch(void* const* d_in, const int* in_sizes, int n_in,
                              void* d_out, int out_size, void* d_ws, size_t ws_size,
                              hipStream_t stream) {
    const float2* kp = (const float2*)d_in[0];
    float* part = (float*)d_ws;   // NPARTS floats, fully overwritten each call
    float* out = (float*)d_out;

    dim3 grid(NTILES, BATCHES);   // 144 x 32 = 4608 two-wave blocks
    loss_sep_kernel<<<grid, 128, 0, stream>>>(kp, part);
    loss_sep_reduce<<<1, 256, 0, stream>>>(part, out);
}

// Round 13
// 67.929 us; speedup vs baseline: 1.0336x; 1.0193x over previous
//
#include <hip/hip_runtime.h>

// loss_separation: sum_{b, i != j} exp(-0.5 * ||kp[b,i] - kp[b,j]||)
// B=32, N=2048 fp32 -> scalar fp32.
// Symmetry: 2*sum_{i<j}; upper-tri 128x128 tile pairs; partials->d_ws + reduce.
// R7: Schraudolph exp2 (fma+cvt) replaced v_exp_f32 (-4.5us -> each trans op
//     ~9.4 issue-cy). R13: bit-hack sqrt replaces v_sqrt_f32 (shr+add, 4cy vs
//     9.4cy): iter 74->52 cy, zero trans ops left. Diag correction stays exact
//     (d2=0 -> s'~8e-20 -> fma rounds to BF_EXP bit-exactly).

#define BATCHES 32
#define NPTS 2048
#define TILE 128
#define TTILES (NPTS / TILE)                 // 16
#define NTPAIRS (TTILES * (TTILES + 1) / 2)  // 136
#define NPARTS (NTPAIRS * BATCHES)           // 4352 = 17 * 256

typedef float vf2 __attribute__((ext_vector_type(2)));
typedef float vf4 __attribute__((ext_vector_type(4)));

// exp2(x) ~= asfloat((int)(x*2^23 + BF)), x <= 0 here.
// K folds -0.5*log2(e) and 2^23. BF = (127 - 0.0564)*2^23 + 0.5.
#define K_EXP  (-6051102.0f)        // -0.72134752 * 8388608
#define BF_EXP (1064880100.0f)      // (127 - 0.0564) * 2^23 + 0.5
#define SQRT_MAGIC 0x1FBD1DF5      // Blinn: sqrt(x) ~= asfloat((asint(x)>>1)+M)

__device__ __forceinline__ float bit_sqrt(float x) {
    return __int_as_float((__float_as_int(x) >> 1) + SQRT_MAGIC);
}

__global__ __launch_bounds__(TILE)
void loss_sep_kernel(const float2* __restrict__ kp, float* __restrict__ part) {
    const int b = blockIdx.y;

    // Decode upper-triangular tile pair (ti <= tj); uniform SALU loop <=16 iters.
    int t = blockIdx.x;
    int ti = 0;
    while (t >= TTILES - ti) { t -= TTILES - ti; ++ti; }
    const int tj = ti + t;
    const bool diag = (ti == tj);

    const int i0 = ti * TILE;
    const int j0 = tj * TILE;
    const int tid = threadIdx.x;

    __shared__ float kjx[TILE];   // SoA so b128 gives 4 consecutive x's
    __shared__ float kjy[TILE];
    {
        const float2 v = kp[(size_t)b * NPTS + j0 + tid];
        kjx[tid] = v.x;
        kjy[tid] = v.y;
    }
    const float2 ki = kp[(size_t)b * NPTS + i0 + tid];
    __syncthreads();

    const vf4* xs4 = reinterpret_cast<const vf4*>(kjx);
    const vf4* ys4 = reinterpret_cast<const vf4*>(kjy);
    const vf2 kx = {ki.x, ki.x};
    const vf2 ky = {ki.y, ki.y};

    vf2 accA = {0.0f, 0.0f}, accB = {0.0f, 0.0f};
    #pragma unroll 4
    for (int jj = 0; jj < TILE / 4; ++jj) {
        const vf4 xs = xs4[jj];              // ds_read_b128 broadcast
        const vf4 ys = ys4[jj];
        const vf2 dx01 = kx - xs.lo;         // v_pk math
        const vf2 dy01 = ky - ys.lo;
        const vf2 dx23 = kx - xs.hi;
        const vf2 dy23 = ky - ys.hi;
        const vf2 d01 = dx01 * dx01 + dy01 * dy01;
        const vf2 d23 = dx23 * dx23 + dy23 * dy23;
        const int e0 = (int)fmaf(bit_sqrt(d01.x), K_EXP, BF_EXP);
        const int e1 = (int)fmaf(bit_sqrt(d01.y), K_EXP, BF_EXP);
        const int e2 = (int)fmaf(bit_sqrt(d23.x), K_EXP, BF_EXP);
        const int e3 = (int)fmaf(bit_sqrt(d23.y), K_EXP, BF_EXP);
        accA += (vf2){__int_as_float(e0), __int_as_float(e1)};
        accB += (vf2){__int_as_float(e2), __int_as_float(e3)};
    }
    const vf2 accp = accA + accB;
    float acc = accp.x + accp.y;
    // Diagonal j==i contributed exactly asfloat((int)BF_EXP) (s'~8e-20,
    // fma rounds to BF_EXP). Remove it.
    if (diag) acc -= __int_as_float((int)BF_EXP);

    // Wave-64 butterfly reduce
    #pragma unroll
    for (int off = 32; off > 0; off >>= 1)
        acc += __shfl_down(acc, off, 64);

    __shared__ float wsum[TILE / 64];
    if ((tid & 63) == 0) wsum[tid >> 6] = acc;
    __syncthreads();

    if (tid == 0) {
        float tot = wsum[0] + wsum[1];
        if (!diag) tot *= 2.0f;  // unordered pair counted once -> weight 2
        part[b * NTPAIRS + blockIdx.x] = tot;  // contention-free store
    }
}

__global__ __launch_bounds__(256)
void loss_sep_reduce(const float* __restrict__ part, float* __restrict__ out) {
    const int tid = threadIdx.x;
    float acc = 0.0f;
    #pragma unroll
    for (int k = 0; k < NPARTS / 256; ++k)      // 17 coalesced strided loads
        acc += part[k * 256 + tid];

    #pragma unroll
    for (int off = 32; off > 0; off >>= 1)
        acc += __shfl_down(acc, off, 64);

    __shared__ float wsum[4];
    if ((tid & 63) == 0) wsum[tid >> 6] = acc;
    __syncthreads();

    if (tid == 0)
        out[0] = wsum[0] + wsum[1] + wsum[2] + wsum[3];
}

extern "C" void kernel_launch(void* const* d_in, const int* in_sizes, int n_in,
                              void* d_out, int out_size, void* d_ws, size_t ws_size,
                              hipStream_t stream) {
    const float2* kp = (const float2*)d_in[0];
    float* part = (float*)d_ws;   // NPARTS floats, fully overwritten each call
    float* out = (float*)d_out;

    dim3 grid(NTPAIRS, BATCHES);  // 136 x 32 = 4352 two-wave blocks
    loss_sep_kernel<<<grid, TILE, 0, stream>>>(kp, part);
    loss_sep_reduce<<<1, 256, 0, stream>>>(part, out);
}